// Round 7
// baseline (511.165 us; speedup 1.0000x reference)
//
#include <hip/hip_runtime.h>
#include <hip/hip_bf16.h>
#include <hip/hip_cooperative_groups.h>

namespace cg = cooperative_groups;

typedef __hip_bfloat16 bf16;
typedef __attribute__((ext_vector_type(8))) short short8;
typedef __attribute__((ext_vector_type(4))) short short4v;
typedef __attribute__((ext_vector_type(4))) float f32x4;

#define NB 16
#define NT 1024
#define ND 500
#define NDP 512               /* padded K/N for MFMA */
#define NTOK (NB * NT)
#define INV_SCALE 0.04472135954999579f   /* 1/sqrt(500) */

__device__ __forceinline__ float b2f(bf16 x) { return __bfloat162float(x); }

__device__ __forceinline__ void gload_lds16(const bf16* g, short* l) {
    __builtin_amdgcn_global_load_lds((const __attribute__((address_space(1))) void*)g,
                                     (__attribute__((address_space(3))) void*)l, 16, 0, 0);
}

/* =====================================================================
 * Core A (HBM-fed GEMMs: proj3, mgemm): BK=32, 3-buffer counted-vmcnt.
 * LDS 48 KB -> 3 blocks/CU.  [verified round 5/6]
 * ===================================================================== */
__device__ __forceinline__ void mfma_core3(const bf16* __restrict__ Ab, int lda,
                                           const bf16* __restrict__ Bb, int ldb,
                                           int nsteps, short* As, short* Bs,
                                           f32x4 (&acc)[4][4]) {
    const int tid = threadIdx.x;
    const int lane = tid & 63;
    const int wave = tid >> 6;
    const int wy = wave >> 1, wx = wave & 1;
    const int m16 = lane & 15, quad = lane >> 4;
    const int srow = wave * 16 + (lane >> 2);
    const int sseg = lane & 3;
    const bf16* a0 = Ab + (size_t)srow * lda + sseg * 8;
    const bf16* a1 = a0 + (size_t)64 * lda;
    const bf16* b0 = Bb + (size_t)srow * ldb + sseg * 8;
    const bf16* b1 = b0 + (size_t)64 * ldb;
    short* aL0 = As + wave * 512;
    short* aL1 = As + 2048 + wave * 512;
    short* bL0 = Bs + wave * 512;
    short* bL1 = Bs + 2048 + wave * 512;
    gload_lds16(a0, aL0);      gload_lds16(a1, aL1);
    gload_lds16(b0, bL0);      gload_lds16(b1, bL1);
    gload_lds16(a0 + 32, aL0 + 4096); gload_lds16(a1 + 32, aL1 + 4096);
    gload_lds16(b0 + 32, bL0 + 4096); gload_lds16(b1 + 32, bL1 + 4096);
    int buf = 0;
    for (int ks = 0; ks < nsteps; ks++) {
        if (ks + 1 < nsteps) { asm volatile("s_waitcnt vmcnt(4)" ::: "memory"); }
        else                 { asm volatile("s_waitcnt vmcnt(0)" ::: "memory"); }
        __builtin_amdgcn_s_barrier();
        if (ks + 2 < nsteps) {
            int nb = buf + 2; if (nb >= 3) nb -= 3;
            const int nxt = nb * 4096;
            const int ko = (ks + 2) * 32;
            gload_lds16(a0 + ko, aL0 + nxt); gload_lds16(a1 + ko, aL1 + nxt);
            gload_lds16(b0 + ko, bL0 + nxt); gload_lds16(b1 + ko, bL1 + nxt);
        }
        const int cur = buf * 4096;
        short8 af[4], bfv[4];
        #pragma unroll
        for (int i = 0; i < 4; i++)
            af[i] = *(const short8*)&As[cur + (wy * 64 + i * 16 + m16) * 32 + quad * 8];
        #pragma unroll
        for (int j = 0; j < 4; j++)
            bfv[j] = *(const short8*)&Bs[cur + (wx * 64 + j * 16 + m16) * 32 + quad * 8];
        #pragma unroll
        for (int i = 0; i < 4; i++)
            #pragma unroll
            for (int j = 0; j < 4; j++)
                acc[i][j] = __builtin_amdgcn_mfma_f32_16x16x32_bf16(af[i], bfv[j], acc[i][j], 0, 0, 0);
        buf = (buf == 2) ? 0 : buf + 1;
    }
}

/* =====================================================================
 * Core B (L2-resident GEMMs: S, PV): BK=64, 2-phase, XOR-swizzled
 * source+read (conflict-free ds_read_b128).  [verified round 4/6]
 * ===================================================================== */
__device__ __forceinline__ void mfma_core64(const bf16* __restrict__ Ab, int lda,
                                            const bf16* __restrict__ Bb, int ldb,
                                            int nsteps /* K/64 */, short* As, short* Bs,
                                            f32x4 (&acc)[4][4]) {
    const int tid = threadIdx.x;
    const int lane = tid & 63;
    const int wave = tid >> 6;
    const int wy = wave >> 1, wx = wave & 1;
    const int m16 = lane & 15, quad = lane >> 4;
    const int sr = lane >> 3;
    const int sseg = (lane & 7) ^ sr;
    const bf16* aP = Ab + (size_t)(wave * 8 + sr) * lda + sseg * 8;
    const bf16* bP = Bb + (size_t)(wave * 8 + sr) * ldb + sseg * 8;
    short* aL = As + wave * 512;
    short* bL = Bs + wave * 512;
    #pragma unroll
    for (int r = 0; r < 4; r++) {
        gload_lds16(aP + (size_t)(r * 32) * lda, aL + r * 2048);
        gload_lds16(bP + (size_t)(r * 32) * ldb, bL + r * 2048);
    }
    asm volatile("s_waitcnt vmcnt(0)" ::: "memory");
    __builtin_amdgcn_s_barrier();
    const int swz = m16 & 7;
    for (int ks = 0; ks < nsteps; ks++) {
        const int cur = (ks & 1) * 8192;
        const int nxt = 8192 - cur;
        if (ks + 1 < nsteps) {
            const int ko = (ks + 1) * 64;
            #pragma unroll
            for (int r = 0; r < 4; r++) {
                gload_lds16(aP + (size_t)(r * 32) * lda + ko, aL + nxt + r * 2048);
                gload_lds16(bP + (size_t)(r * 32) * ldb + ko, bL + nxt + r * 2048);
            }
        }
        #pragma unroll
        for (int kk = 0; kk < 2; kk++) {
            short8 af[4], bfv[4];
            #pragma unroll
            for (int i = 0; i < 4; i++)
                af[i] = *(const short8*)&As[cur + (wy * 64 + i * 16 + m16) * 64 +
                                            (((kk * 4 + quad) ^ swz) * 8)];
            #pragma unroll
            for (int j = 0; j < 4; j++)
                bfv[j] = *(const short8*)&Bs[cur + (wx * 64 + j * 16 + m16) * 64 +
                                             (((kk * 4 + quad) ^ swz) * 8)];
            #pragma unroll
            for (int i = 0; i < 4; i++)
                #pragma unroll
                for (int j = 0; j < 4; j++)
                    acc[i][j] = __builtin_amdgcn_mfma_f32_16x16x32_bf16(af[i], bfv[j], acc[i][j], 0, 0, 0);
        }
        asm volatile("s_waitcnt vmcnt(0)" ::: "memory");
        __builtin_amdgcn_s_barrier();
    }
}

/* =====================================================================
 * setup_mega: V^T transpose | K_w,Q_w -> bf16 | u,v,c0 GEMVs | build_g
 * ===================================================================== */
__global__ void setup_mega(const float* __restrict__ V_w,
                           const float* __restrict__ K_w, const float* __restrict__ Q_w,
                           const float* __restrict__ K_b, const float* __restrict__ Q_b,
                           const int* __restrict__ words, const int* __restrict__ pos,
                           const int* __restrict__ ner, const int* __restrict__ chunks,
                           const int* __restrict__ subj_pos, const int* __restrict__ obj_pos,
                           const int* __restrict__ on_path, const float* __restrict__ dep_feat,
                           const float* __restrict__ emb_w, const float* __restrict__ pos_w,
                           const float* __restrict__ ner_w, const float* __restrict__ chunk_w,
                           const float* __restrict__ position_w,
                           bf16* __restrict__ WtV, bf16* __restrict__ Kbf, bf16* __restrict__ Qbf,
                           float* __restrict__ uvbuf, bf16* __restrict__ g) {
    int blk = blockIdx.x, tid = threadIdx.x;
    if (blk < 256) {                          /* V^T: Wt[n][k] = V_w[k][n] */
        __shared__ float t[32][33];
        int n0 = (blk & 15) * 32, k0 = (blk >> 4) * 32;
        int a = tid & 31, bq = tid >> 5;
        #pragma unroll
        for (int it = 0; it < 4; it++) {
            int k = k0 + bq + it * 8, n = n0 + a;
            t[bq + it * 8][a] = (k < ND && n < ND) ? V_w[k * ND + n] : 0.f;
        }
        __syncthreads();
        #pragma unroll
        for (int it = 0; it < 4; it++) {
            int n = n0 + bq + it * 8;
            WtV[(size_t)n * NDP + k0 + a] = __float2bfloat16(t[a][bq + it * 8]);
        }
    } else if (blk < 768) {                   /* cvt K_w -> Kbf (padded) */
        int row = blk - 256;
        bf16* dst = Kbf + (size_t)row * NDP;
        for (int c = tid; c < NDP; c += 256)
            dst[c] = __float2bfloat16((row < ND && c < ND) ? K_w[row * ND + c] : 0.f);
    } else if (blk < 1280) {                  /* cvt Q_w -> Qbf */
        int row = blk - 768;
        bf16* dst = Qbf + (size_t)row * NDP;
        for (int c = tid; c < NDP; c += 256)
            dst[c] = __float2bfloat16((row < ND && c < ND) ? Q_w[row * ND + c] : 0.f);
    } else if (blk < 1288) {                  /* u[k] = K_w[k,:] . Q_b */
        int k = (blk - 1280) * 64 + tid;
        if (tid < 64) {
            float s = 0.f;
            if (k < ND) for (int n = 0; n < ND; n++) s += K_w[(size_t)k * ND + n] * Q_b[n];
            uvbuf[k] = s;
        }
    } else if (blk < 1296) {                  /* v[k] = Q_w[k,:] . K_b */
        int k = (blk - 1288) * 64 + tid;
        if (tid < 64) {
            float s = 0.f;
            if (k < ND) for (int n = 0; n < ND; n++) s += Q_w[(size_t)k * ND + n] * K_b[n];
            uvbuf[512 + k] = s;
        }
    } else if (blk == 1296) {                 /* c0 = K_b . Q_b */
        if (tid == 0) {
            float s = 0.f;
            for (int n = 0; n < ND; n++) s += K_b[n] * Q_b[n];
            uvbuf[1024] = s;
        }
    } else {                                  /* build_g */
        int tok = blk - 1297;
        int w = words[tok], p = pos[tok], n = ner[tok], ck = chunks[tok];
        int sp = subj_pos[tok], op = obj_pos[tok], onp = on_path[tok];
        bf16* gr = g + (size_t)tok * NDP;
        for (int d = tid; d < NDP; d += 256) {
            float v;
            if      (d < 300) v = emb_w[(size_t)w * 300 + d];
            else if (d < 335) v = pos_w[p * 35 + (d - 300)];
            else if (d < 365) v = ner_w[n * 30 + (d - 335)];
            else if (d < 395) v = chunk_w[ck * 30 + (d - 365)];
            else if (d < 425) v = position_w[sp * 30 + (d - 395)];
            else if (d < 455) v = position_w[op * 30 + (d - 425)];
            else if (d == 455) v = (float)onp;
            else if (d < 500) v = dep_feat[(size_t)tok * 44 + (d - 456)];
            else              v = 0.f;
            gr[d] = __float2bfloat16(v);
        }
    }
}

/* ---- M = K_w @ Q_w^T, stored transposed: Mt[k'][k] (B-operand layout) ---- */
__global__ __launch_bounds__(256) void mgemm(const bf16* __restrict__ Kbf, const bf16* __restrict__ Qbf,
                                             bf16* __restrict__ Mt) {
    __shared__ short LB[24576];
    short* As = LB;
    short* Bs = LB + 12288;
    f32x4 acc[4][4] = {};
    int row0 = blockIdx.x * 128, col0 = blockIdx.y * 128;
    mfma_core3(Kbf + (size_t)row0 * NDP, NDP, Qbf + (size_t)col0 * NDP, NDP, NDP / 32, As, Bs, acc);
    const int tid = threadIdx.x, lane = tid & 63, wave = tid >> 6;
    const int wx = wave & 1, wy = wave >> 1, m16 = lane & 15, quad = lane >> 4;
    bf16* Ct = (bf16*)LB;
    __syncthreads();
    #pragma unroll
    for (int h = 0; h < 2; h++) {
        if (wy == h) {
            #pragma unroll
            for (int j = 0; j < 4; j++) {
                int cl = wx * 64 + j * 16 + m16;
                #pragma unroll
                for (int i = 0; i < 4; i++)
                    #pragma unroll
                    for (int reg = 0; reg < 4; reg++)
                        Ct[(i * 16 + quad * 4 + reg) * 128 + cl] = __float2bfloat16(acc[i][j][reg]);
            }
        }
        __syncthreads();
        int cl2 = tid & 127, sh = tid >> 7;
        bf16* dst = Mt + ((size_t)(col0 + cl2)) * NDP + row0 + h * 64 + sh * 32;
        #pragma unroll
        for (int kk = 0; kk < 8; kk++) {
            short4v o;
            #pragma unroll
            for (int e = 0; e < 4; e++)
                ((bf16*)&o)[e] = Ct[(sh * 32 + kk * 4 + e) * 128 + cl2];
            *(short4v*)(dst + kk * 4) = o;
        }
        __syncthreads();
    }
}

/* =====================================================================
 * phaseA (cooperative, 256 blocks x 512 thr, 1 block/CU):
 *  S1 pool partials -> S2 pool-reduce + q GEMV -> S3 w2 GEMV ->
 *  S4 klog + a/b vectors -> S5 c partials (softmax fused inline) ->
 *  S6 m GEMV.   Replaces 7 kernel launches.
 * ===================================================================== */
__global__ __launch_bounds__(512) void phaseA(
        const bf16* __restrict__ g, const int* __restrict__ subj_pos,
        const float* __restrict__ Wq_w, const float* __restrict__ Wq_b,
        const float* __restrict__ Wc_w, const float* __restrict__ Wc_b,
        const float* __restrict__ Wk_w, const float* __restrict__ Wk_b,
        const float* __restrict__ Wm_w, const float* __restrict__ Wm_b,
        const float* __restrict__ uvbuf,
        float* __restrict__ part, float* __restrict__ subj, float* __restrict__ qb,
        float* __restrict__ w2, float* __restrict__ klog,
        float* __restrict__ a_vec, float* __restrict__ b_vec, float* __restrict__ mv) {
    cg::grid_group grid = cg::this_grid();
    __shared__ float sh[4096];                /* 16 KB scratch, reused per stage */
    const int blk = blockIdx.x, tid = threadIdx.x;

    /* ---- S1: pool partials. blk=(b,ch); thr=(ts 0..7, o 0..63) ---- */
    {
        int b = blk >> 4, ch = blk & 15;
        int ts = tid >> 6, o = tid & 63;
        const int* sp = subj_pos + b * NT;
        const bf16* gb = g + ((size_t)b * NT) * NDP + o * 8;
        float mx[8];
        #pragma unroll
        for (int i = 0; i < 8; i++) mx[i] = -INFINITY;
        #pragma unroll
        for (int it = 0; it < 8; it++) {
            int t = ch * 64 + ts + it * 8;
            int masked = (sp[t] != 0);
            short8 v8 = *(const short8*)(gb + (size_t)t * NDP);
            #pragma unroll
            for (int i = 0; i < 8; i++) {
                float v = masked ? -1e12f : b2f(((bf16*)&v8)[i]);
                mx[i] = fmaxf(mx[i], v);
            }
        }
        #pragma unroll
        for (int i = 0; i < 8; i++) sh[tid * 8 + i] = mx[i];
        __syncthreads();
        if (ts == 0) {
            float r[8];
            #pragma unroll
            for (int i = 0; i < 8; i++) r[i] = sh[o * 8 + i];
            for (int s = 1; s < 8; s++)
                #pragma unroll
                for (int i = 0; i < 8; i++) r[i] = fmaxf(r[i], sh[(s * 64 + o) * 8 + i]);
            float* pr = part + ((size_t)(b * 16 + ch)) * NDP + o * 8;
            #pragma unroll
            for (int i = 0; i < 8; i++) pr[i] = r[i];
        }
        __syncthreads();
    }
    grid.sync();

    /* ---- S2: pool-reduce + subj + q = relu(subj@(Wq0+Wq1)+bq). 64 blocks ---- */
    if (blk < 64) {
        int b = blk >> 2, dch = blk & 3;
        float* xs = sh; float* red = sh + 512;
        float mx = -INFINITY;
        #pragma unroll
        for (int s = 0; s < 16; s++) mx = fmaxf(mx, part[((size_t)(b * 16 + s)) * NDP + tid]);
        xs[tid] = (tid < ND) ? mx : 0.f;
        if (dch == 0 && tid < ND) subj[b * ND + tid] = mx;
        __syncthreads();
        int jg = tid >> 7, dl = tid & 127, d = dch * 128 + dl;
        float acc = 0.f;
        if (d < ND) {
            int j0 = jg * 125;
            const float* w0 = Wq_w + (size_t)j0 * ND + d;
            const float* w1 = w0 + (size_t)ND * ND;
            #pragma unroll 5
            for (int j = 0; j < 125; j++)
                acc += xs[j0 + j] * (w0[(size_t)j * ND] + w1[(size_t)j * ND]);
        }
        red[tid] = acc;
        __syncthreads();
        if (jg == 0 && d < ND) {
            float s = (red[dl] + red[128 + dl]) + (red[256 + dl] + red[384 + dl]);
            qb[b * ND + d] = fmaxf(s + Wq_b[d], 0.f);
        }
    }
    grid.sync();

    /* ---- S3: w2 = relu(q@Wc0+bc)*Wk. 64 blocks ---- */
    if (blk < 64) {
        int b = blk >> 2, dch = blk & 3;
        float* xs = sh; float* red = sh + 512;
        xs[tid] = (tid < ND) ? qb[b * ND + tid] : 0.f;
        __syncthreads();
        int jg = tid >> 7, dl = tid & 127, d = dch * 128 + dl;
        float acc = 0.f;
        if (d < ND) {
            int j0 = jg * 125;
            const float* w0 = Wc_w + (size_t)j0 * ND + d;
            #pragma unroll 5
            for (int j = 0; j < 125; j++)
                acc += xs[j0 + j] * w0[(size_t)j * ND];
        }
        red[tid] = acc;
        __syncthreads();
        if (jg == 0 && d < ND) {
            float s = (red[dl] + red[128 + dl]) + (red[256 + dl] + red[384 + dl]);
            w2[b * ND + d] = fmaxf(s + Wc_b[d], 0.f) * Wk_w[d];
        }
    }
    grid.sync();

    /* ---- S4: klog + a=g.u, b=g.v. 2048 waves x 8 tokens ---- */
    {
        int w = blk * 8 + (tid >> 6);
        int lane = tid & 63;
        const float* ur = uvbuf + lane * 8;
        const float* vr = uvbuf + 512 + lane * 8;
        for (int it = 0; it < 8; it++) {
            int tok = w * 8 + it;
            int b = tok >> 10;
            const bf16* gr = g + (size_t)tok * NDP + lane * 8;
            const float* wr = w2 + b * ND + lane * 8;
            short8 v8 = *(const short8*)gr;
            float aw = 0.f, au = 0.f, av = 0.f;
            #pragma unroll
            for (int i = 0; i < 8; i++) {
                float gv = b2f(((bf16*)&v8)[i]);
                aw += gv * wr[i]; au += gv * ur[i]; av += gv * vr[i];
            }
            #pragma unroll
            for (int off = 32; off; off >>= 1) {
                aw += __shfl_down(aw, off, 64);
                au += __shfl_down(au, off, 64);
                av += __shfl_down(av, off, 64);
            }
            if (lane == 0) {
                klog[tok] = aw + Wk_b[0];
                a_vec[tok] = au;
                b_vec[tok] = av;
            }
        }
    }
    grid.sync();

    /* ---- S5: c partials with inline softmax. blk=(b,ch) ---- */
    {
        int b = blk >> 4, ch = blk & 15;
        const float* kl = klog + b * NT;
        float m = fmaxf(kl[tid], kl[512 + tid]);
        sh[tid] = m; __syncthreads();
        for (int s = 256; s; s >>= 1) { if (tid < s) sh[tid] = fmaxf(sh[tid], sh[tid + s]); __syncthreads(); }
        float mm = sh[0]; __syncthreads();
        float sum = expf(kl[tid] - mm) + expf(kl[512 + tid] - mm);
        sh[tid] = sum; __syncthreads();
        for (int s = 256; s; s >>= 1) { if (tid < s) sh[tid] += sh[tid + s]; __syncthreads(); }
        float inv = 1.f / sh[0]; __syncthreads();
        int ts = tid >> 6, o = tid & 63;
        const bf16* gb = g + ((size_t)b * NT) * NDP + o * 8;
        float acc[8] = {};
        #pragma unroll
        for (int it = 0; it < 8; it++) {
            int t = ch * 64 + ts + it * 8;
            float kv = expf(kl[t] - mm) * inv;
            short8 v8 = *(const short8*)(gb + (size_t)t * NDP);
            #pragma unroll
            for (int i = 0; i < 8; i++) acc[i] += kv * b2f(((bf16*)&v8)[i]);
        }
        #pragma unroll
        for (int i = 0; i < 8; i++) sh[tid * 8 + i] = acc[i];
        __syncthreads();
        if (ts == 0) {
            float r[8] = {};
            for (int s = 0; s < 8; s++)
                #pragma unroll
                for (int i = 0; i < 8; i++) r[i] += sh[(s * 64 + o) * 8 + i];
            float* pr = part + ((size_t)(b * 16 + ch)) * NDP + o * 8;
            #pragma unroll
            for (int i = 0; i < 8; i++) pr[i] = r[i];
        }
        __syncthreads();
    }
    grid.sync();

    /* ---- S6: c-reduce + m = relu(c@Wm0 + subj@(Wm1+Wm2) + bm). 64 blocks ---- */
    if (blk < 64) {
        int b = blk >> 2, dch = blk & 3;
        float* cs = sh; float* ss = sh + 512; float* red = sh + 1024;
        float a = 0.f;
        #pragma unroll
        for (int s = 0; s < 16; s++) a += part[((size_t)(b * 16 + s)) * NDP + tid];
        cs[tid] = (tid < ND) ? a : 0.f;
        ss[tid] = (tid < ND) ? subj[b * ND + tid] : 0.f;
        __syncthreads();
        int jg = tid >> 7, dl = tid & 127, d = dch * 128 + dl;
        float acc = 0.f;
        if (d < ND) {
            int j0 = jg * 125;
            const float* w0 = Wm_w + (size_t)j0 * ND + d;
            const float* w1 = w0 + (size_t)ND * ND;
            const float* w2p = w0 + (size_t)2 * ND * ND;
            #pragma unroll 5
            for (int j = 0; j < 125; j++) {
                acc += cs[j0 + j] * w0[(size_t)j * ND];
                acc += ss[j0 + j] * (w1[(size_t)j * ND] + w2p[(size_t)j * ND]);
            }
        }
        red[tid] = acc;
        __syncthreads();
        if (jg == 0 && d < ND) {
            float s = (red[dl] + red[128 + dl]) + (red[256 + dl] + red[384 + dl]);
            mv[b * ND + d] = fmaxf(s + Wm_b[d], 0.f);
        }
    }
}

/* ---- projections: z=0 h=g@M (normal store), z=1 value (transposed Vt store) ---- */
__global__ __launch_bounds__(256) void mfma_proj3(const bf16* __restrict__ g, const bf16* __restrict__ Mt,
                                                  const bf16* __restrict__ WtV, const float* __restrict__ bV,
                                                  bf16* __restrict__ gM, bf16* __restrict__ valT) {
    __shared__ short LB[24576];
    short* As = LB;
    short* Bs = LB + 12288;
    f32x4 acc[4][4] = {};
    const int zz = blockIdx.z;
    const bf16* Wt = (zz == 0) ? Mt : WtV;
    int row0 = blockIdx.x * 128, col0 = blockIdx.y * 128;
    mfma_core3(g + (size_t)row0 * NDP, NDP, Wt + (size_t)col0 * NDP, NDP, NDP / 32, As, Bs, acc);
    const int tid = threadIdx.x, lane = tid & 63, wave = tid >> 6;
    const int wx = wave & 1, wy = wave >> 1, m16 = lane & 15, quad = lane >> 4;
    bf16* Ct = (bf16*)LB;
    int rl = tid >> 4, cs = (tid & 15) * 8;
    int bI = row0 >> 10, sBase = row0 & 1023;
    __syncthreads();
    #pragma unroll
    for (int h = 0; h < 2; h++) {
        if (wy == h) {
            #pragma unroll
            for (int j = 0; j < 4; j++) {
                int cl = wx * 64 + j * 16 + m16;
                int cg = col0 + cl;
                float bv = (zz == 1 && cg < ND) ? bV[cg] : 0.f;
                bool ok = (cg < ND);
                #pragma unroll
                for (int i = 0; i < 4; i++)
                    #pragma unroll
                    for (int reg = 0; reg < 4; reg++)
                        Ct[(i * 16 + quad * 4 + reg) * 128 + cl] =
                            __float2bfloat16(ok ? (acc[i][j][reg] + bv) : 0.f);
            }
        }
        __syncthreads();
        if (zz == 0) {
            #pragma unroll
            for (int p = 0; p < 4; p++) {
                int row_l = p * 16 + rl;
                *(short8*)(gM + (size_t)(row0 + h * 64 + row_l) * NDP + col0 + cs) =
                    *(const short8*)&Ct[row_l * 128 + cs];
            }
        } else {
            int cl2 = tid & 127, sh = tid >> 7;
            bf16* dst = valT + ((size_t)(bI * NDP + col0 + cl2)) * NT + sBase + h * 64 + sh * 32;
            #pragma unroll
            for (int kk = 0; kk < 8; kk++) {
                short4v o;
                #pragma unroll
                for (int e = 0; e < 4; e++)
                    ((bf16*)&o)[e] = Ct[(sh * 32 + kk * 4 + e) * 128 + cl2];
                *(short4v*)(dst + kk * 4) = o;
            }
        }
        __syncthreads();
    }
}

/* ---- MFMA S = (g@M) @ g^T: z-XCD affinity, core64 ---- */
__global__ __launch_bounds__(256) void mfma_S(const bf16* __restrict__ gM, const bf16* __restrict__ g,
                                              bf16* __restrict__ S) {
    __shared__ short LB[32768];
    short* As = LB;
    short* Bs = LB + 16384;
    f32x4 acc[4][4] = {};
    int lin = blockIdx.x;
    int xcd = lin & 7, j = lin >> 3;
    int i = j & 63, z = xcd + 8 * (j >> 6);
    int bx = i & 7, by = i >> 3;
    int row0 = bx * 128, col0 = by * 128;
    const bf16* kb = gM + (size_t)z * NT * NDP;
    const bf16* qb = g + (size_t)z * NT * NDP;
    mfma_core64(kb + (size_t)row0 * NDP, NDP, qb + (size_t)col0 * NDP, NDP, NDP / 64, As, Bs, acc);
    bf16* Sb = S + ((size_t)z << 20);
    const int tid = threadIdx.x, lane = tid & 63, wave = tid >> 6;
    const int wx = wave & 1, wy = wave >> 1, m16 = lane & 15, quad = lane >> 4;
    bf16* Ct = (bf16*)LB;
    int rl = tid >> 4, cs = (tid & 15) * 8;
    __syncthreads();
    #pragma unroll
    for (int h = 0; h < 2; h++) {
        if (wy == h) {
            #pragma unroll
            for (int j2 = 0; j2 < 4; j2++) {
                int cl = wx * 64 + j2 * 16 + m16;
                #pragma unroll
                for (int i2 = 0; i2 < 4; i2++)
                    #pragma unroll
                    for (int reg = 0; reg < 4; reg++)
                        Ct[(i2 * 16 + quad * 4 + reg) * 128 + cl] = __float2bfloat16(acc[i2][j2][reg]);
            }
        }
        __syncthreads();
        #pragma unroll
        for (int p = 0; p < 4; p++) {
            int row_l = p * 16 + rl;
            *(short8*)(Sb + (((size_t)(row0 + h * 64 + row_l)) << 10) + col0 + cs) =
                *(const short8*)&Ct[row_l * 128 + cs];
        }
        __syncthreads();
    }
}

/* ---- double softmax with bias terms a[t]+b[s]+c0; in-place P2 ---- */
__global__ __launch_bounds__(256) void attn_rows(bf16* __restrict__ S,
                                                 const float* __restrict__ a_vec,
                                                 const float* __restrict__ b_vec,
                                                 const float* __restrict__ uvbuf,
                                                 float* __restrict__ att_out) {
    int lin = blockIdx.x;
    int xcd = lin & 7, t2 = lin >> 3;
    int i2 = t2 & 255, zh = t2 >> 8;
    int z = xcd + 8 * zh;
    int gr = z * 1024 + i2 * 4 + (threadIdx.x >> 6);
    int t = gr & 1023;
    int lane = threadIdx.x & 63;
    bf16* row = S + ((size_t)gr << 10) + lane * 16;
    short8 r0 = *(const short8*)row;
    short8 r1 = *(const short8*)(row + 8);
    float add = a_vec[gr] + uvbuf[1024];
    const float* bvp = b_vec + ((size_t)z << 10) + lane * 16;
    f32x4 bv0 = *(const f32x4*)(bvp);
    f32x4 bv1 = *(const f32x4*)(bvp + 4);
    f32x4 bv2 = *(const f32x4*)(bvp + 8);
    f32x4 bv3 = *(const f32x4*)(bvp + 12);
    float v[16];
    #pragma unroll
    for (int i = 0; i < 8; i++) { v[i] = b2f(((bf16*)&r0)[i]); v[8 + i] = b2f(((bf16*)&r1)[i]); }
    #pragma unroll
    for (int i = 0; i < 4; i++) {
        v[i]      += add + bv0[i];
        v[4 + i]  += add + bv1[i];
        v[8 + i]  += add + bv2[i];
        v[12 + i] += add + bv3[i];
    }
    float m = -INFINITY;
    #pragma unroll
    for (int i = 0; i < 16; i++) m = fmaxf(m, v[i]);
    #pragma unroll
    for (int off = 32; off; off >>= 1) m = fmaxf(m, __shfl_xor(m, off, 64));
    float s1 = 0.f, s2 = 0.f, dg = 0.f;
    int tloc = t - lane * 16;
    #pragma unroll
    for (int i = 0; i < 16; i++) {
        float e1 = expf(v[i] - m);
        float e2 = expf((v[i] - m) * INV_SCALE);
        s1 += e1; s2 += e2;
        if (i == tloc) dg = e1;
        v[i] = e2;
    }
    #pragma unroll
    for (int off = 32; off; off >>= 1) {
        s1 += __shfl_xor(s1, off, 64);
        s2 += __shfl_xor(s2, off, 64);
        dg += __shfl_xor(dg, off, 64);
    }
    if (lane == 0) att_out[gr] = (1.f - dg / s1) * INV_SCALE;
    float inv2 = 1.f / s2;
    #pragma unroll
    for (int i = 0; i < 8; i++) {
        ((bf16*)&r0)[i] = __float2bfloat16(v[i] * inv2);
        ((bf16*)&r1)[i] = __float2bfloat16(v[8 + i] * inv2);
    }
    *(short8*)row = r0;
    *(short8*)(row + 8) = r1;
}

/* ---- MFMA PV: z-XCD affinity, core64 ---- */
__global__ __launch_bounds__(256) void mfma_PV(const bf16* __restrict__ S, const bf16* __restrict__ valueT,
                                               const float* __restrict__ mvec, float* __restrict__ outp) {
    __shared__ short LB[32768];
    short* As = LB;
    short* Bs = LB + 16384;
    f32x4 acc[4][4] = {};
    int lin = blockIdx.x;
    int xcd = lin & 7, j = lin >> 3;
    int i = j & 31, z = xcd + 8 * (j >> 5);
    int bx = i & 7, by = i >> 3;
    int row0 = bx * 128, col0 = by * 128;
    const bf16* P2 = S + ((size_t)z << 20);
    const bf16* Vt = valueT + (size_t)z * NDP * NT;
    mfma_core64(P2 + (size_t)row0 * NT, NT, Vt + (size_t)col0 * NT, NT, NT / 64, As, Bs, acc);
    const int tid = threadIdx.x, lane = tid & 63, wave = tid >> 6;
    const int wx = wave & 1, wy = wave >> 1, m16 = lane & 15, quad = lane >> 4;
    float* Ct = (float*)LB;
    int rl = tid >> 4, cs = (tid & 15) * 8;
    __syncthreads();
    #pragma unroll
    for (int h = 0; h < 2; h++) {
        if (wy == h) {
            #pragma unroll
            for (int j2 = 0; j2 < 4; j2++) {
                int cl = wx * 64 + j2 * 16 + m16;
                int cg = col0 + cl;
                float mm = (cg < ND) ? mvec[z * ND + cg] : 0.f;
                #pragma unroll
                for (int i2 = 0; i2 < 4; i2++)
                    #pragma unroll
                    for (int reg = 0; reg < 4; reg++)
                        Ct[(i2 * 16 + quad * 4 + reg) * 128 + cl] = acc[i2][j2][reg] * mm;
            }
        }
        __syncthreads();
        #pragma unroll
        for (int p = 0; p < 4; p++) {
            int row_l = p * 16 + rl;
            int r = row0 + h * 64 + row_l;
            float* orow = outp + (size_t)(z * NT + r) * ND + col0 + cs;
            const float* src = &Ct[row_l * 128 + cs];
            if (col0 + cs + 8 <= ND) {
                *(f32x4*)orow = *(const f32x4*)src;
                *(f32x4*)(orow + 4) = *(const f32x4*)(src + 4);
            } else {
                #pragma unroll
                for (int e = 0; e < 8; e++)
                    if (col0 + cs + e < ND) orow[e] = src[e];
            }
        }
        __syncthreads();
    }
}

extern "C" void kernel_launch(void* const* d_in, const int* in_sizes, int n_in,
                              void* d_out, int out_size, void* d_ws, size_t ws_size,
                              hipStream_t stream) {
    const int*   words     = (const int*)d_in[0];
    const int*   pos       = (const int*)d_in[2];
    const int*   ner       = (const int*)d_in[3];
    const int*   subj_pos  = (const int*)d_in[4];
    const int*   obj_pos   = (const int*)d_in[5];
    const int*   chunks    = (const int*)d_in[6];
    const int*   on_path   = (const int*)d_in[7];
    const float* dep_feat  = (const float*)d_in[8];
    const float* emb_w     = (const float*)d_in[9];
    const float* pos_w     = (const float*)d_in[10];
    const float* ner_w     = (const float*)d_in[11];
    const float* chunk_w   = (const float*)d_in[12];
    const float* position_w= (const float*)d_in[13];
    const float* Wq_w      = (const float*)d_in[14];
    const float* Wq_b      = (const float*)d_in[15];
    const float* Wc_w      = (const float*)d_in[16];
    const float* Wc_b      = (const float*)d_in[17];
    const float* Wk_w      = (const float*)d_in[18];
    const float* Wk_b      = (const float*)d_in[19];
    const float* Wm_w      = (const float*)d_in[20];
    const float* Wm_b      = (const float*)d_in[21];
    const float* K_w       = (const float*)d_in[22];
    const float* K_b       = (const float*)d_in[23];
    const float* Q_w       = (const float*)d_in[24];
    const float* Q_b       = (const float*)d_in[25];
    const float* V_w       = (const float*)d_in[26];
    const float* V_b       = (const float*)d_in[27];

    float* out_main = (float*)d_out;
    float* out_att  = out_main + (size_t)NTOK * ND;

    /* ---- ws layout ---- */
    char* wp = (char*)d_ws;
    float* subj = (float*)wp; wp += (size_t)NB * ND * 4;
    float* qb   = (float*)wp; wp += (size_t)NB * ND * 4;
    float* w2   = (float*)wp; wp += (size_t)NB * ND * 4;
    float* cb   = (float*)wp; wp += (size_t)NB * ND * 4;   /* unused */
    float* mv   = (float*)wp; wp += (size_t)NB * ND * 4;
    float* klog = (float*)wp; wp += (size_t)NB * NT * 4;
    float* kbuf = (float*)wp; wp += (size_t)NB * NT * 4;   /* unused (kept for layout) */
    float* part = (float*)wp; wp += (size_t)NB * 32 * NDP * 4;
    bf16* g     = (bf16*)wp;  wp += (size_t)NTOK * NDP * 2;
    bf16* Wt    = (bf16*)wp;  wp += (size_t)3 * NDP * NDP * 2;   /* slot0=V^T, slot1=Mt */
    bf16* kqv   = (bf16*)wp;  wp += (size_t)3 * NTOK * NDP * 2;  /* slot0=gM; slot1 carved below */
    bf16* valT  = (bf16*)wp;  wp += (size_t)NTOK * NDP * 2;
    bf16* S     = (bf16*)wp;                                     /* 32 MB */

    bf16* WtV = Wt;
    bf16* Mt  = Wt + (size_t)NDP * NDP;
    bf16* gM  = kqv;
    bf16* Kbf = kqv + (size_t)NTOK * NDP;
    bf16* Qbf = Kbf + (size_t)NDP * NDP;
    float* uvbuf = (float*)(Qbf + (size_t)NDP * NDP);   /* u[512] v[512] c0 */
    float* a_vec = uvbuf + 2048;
    float* b_vec = a_vec + NTOK;
    (void)cb; (void)kbuf;

    /* setup: V^T | K/Q->bf16 | u,v,c0 | build_g */
    setup_mega<<<1297 + NTOK, 256, 0, stream>>>(V_w, K_w, Q_w, K_b, Q_b,
                                                words, pos, ner, chunks, subj_pos, obj_pos,
                                                on_path, dep_feat, emb_w, pos_w, ner_w,
                                                chunk_w, position_w, WtV, Kbf, Qbf, uvbuf, g);
    mgemm<<<dim3(4, 4), 256, 0, stream>>>(Kbf, Qbf, Mt);

    /* phase A: single cooperative kernel (replaces 7 launches) */
    {
        const bf16* g_c = g;
        void* args[] = {
            (void*)&g_c, (void*)&subj_pos,
            (void*)&Wq_w, (void*)&Wq_b, (void*)&Wc_w, (void*)&Wc_b,
            (void*)&Wk_w, (void*)&Wk_b, (void*)&Wm_w, (void*)&Wm_b,
            (void*)&uvbuf,
            (void*)&part, (void*)&subj, (void*)&qb, (void*)&w2,
            (void*)&klog, (void*)&a_vec, (void*)&b_vec, (void*)&mv };
        hipLaunchCooperativeKernel((const void*)phaseA, dim3(256), dim3(512),
                                   args, 0, stream);
    }

    /* phase B */
    mfma_proj3<<<dim3(NTOK / 128, NDP / 128, 2), 256, 0, stream>>>(g, Mt, WtV, V_b, gM, valT);
    mfma_S<<<1024, 256, 0, stream>>>(gM, g, S);
    attn_rows<<<NTOK / 4, 256, 0, stream>>>(S, a_vec, b_vec, uvbuf, out_att);
    mfma_PV<<<512, 256, 0, stream>>>(S, valT, mv, out_main);

    (void)in_sizes; (void)n_in; (void)out_size; (void)ws_size;
}

// Round 8
// 330.157 us; speedup vs baseline: 1.5483x; 1.5483x over previous
//
#include <hip/hip_runtime.h>
#include <hip/hip_bf16.h>

typedef __hip_bfloat16 bf16;
typedef __attribute__((ext_vector_type(8))) short short8;
typedef __attribute__((ext_vector_type(4))) short short4v;
typedef __attribute__((ext_vector_type(4))) float f32x4;

#define NB 16
#define NT 1024
#define ND 500
#define NDP 512               /* padded K/N for MFMA */
#define NTOK (NB * NT)
#define TSP 32                /* t split for pool/c kernels */
#define INV_SCALE 0.04472135954999579f   /* 1/sqrt(500) */

__device__ __forceinline__ float b2f(bf16 x) { return __bfloat162float(x); }

__device__ __forceinline__ void gload_lds16(const bf16* g, short* l) {
    __builtin_amdgcn_global_load_lds((const __attribute__((address_space(1))) void*)g,
                                     (__attribute__((address_space(3))) void*)l, 16, 0, 0);
}

/* =====================================================================
 * Core A (HBM-fed GEMMs: proj3, mgemm): BK=32, 3-buffer counted-vmcnt.
 * LDS 48 KB -> 3 blocks/CU.  [verified rounds 5/6]
 * ===================================================================== */
__device__ __forceinline__ void mfma_core3(const bf16* __restrict__ Ab, int lda,
                                           const bf16* __restrict__ Bb, int ldb,
                                           int nsteps, short* As, short* Bs,
                                           f32x4 (&acc)[4][4]) {
    const int tid = threadIdx.x;
    const int lane = tid & 63;
    const int wave = tid >> 6;
    const int wy = wave >> 1, wx = wave & 1;
    const int m16 = lane & 15, quad = lane >> 4;
    const int srow = wave * 16 + (lane >> 2);
    const int sseg = lane & 3;
    const bf16* a0 = Ab + (size_t)srow * lda + sseg * 8;
    const bf16* a1 = a0 + (size_t)64 * lda;
    const bf16* b0 = Bb + (size_t)srow * ldb + sseg * 8;
    const bf16* b1 = b0 + (size_t)64 * ldb;
    short* aL0 = As + wave * 512;
    short* aL1 = As + 2048 + wave * 512;
    short* bL0 = Bs + wave * 512;
    short* bL1 = Bs + 2048 + wave * 512;
    gload_lds16(a0, aL0);      gload_lds16(a1, aL1);
    gload_lds16(b0, bL0);      gload_lds16(b1, bL1);
    gload_lds16(a0 + 32, aL0 + 4096); gload_lds16(a1 + 32, aL1 + 4096);
    gload_lds16(b0 + 32, bL0 + 4096); gload_lds16(b1 + 32, bL1 + 4096);
    int buf = 0;
    for (int ks = 0; ks < nsteps; ks++) {
        if (ks + 1 < nsteps) { asm volatile("s_waitcnt vmcnt(4)" ::: "memory"); }
        else                 { asm volatile("s_waitcnt vmcnt(0)" ::: "memory"); }
        __builtin_amdgcn_s_barrier();
        if (ks + 2 < nsteps) {
            int nb = buf + 2; if (nb >= 3) nb -= 3;
            const int nxt = nb * 4096;
            const int ko = (ks + 2) * 32;
            gload_lds16(a0 + ko, aL0 + nxt); gload_lds16(a1 + ko, aL1 + nxt);
            gload_lds16(b0 + ko, bL0 + nxt); gload_lds16(b1 + ko, bL1 + nxt);
        }
        const int cur = buf * 4096;
        short8 af[4], bfv[4];
        #pragma unroll
        for (int i = 0; i < 4; i++)
            af[i] = *(const short8*)&As[cur + (wy * 64 + i * 16 + m16) * 32 + quad * 8];
        #pragma unroll
        for (int j = 0; j < 4; j++)
            bfv[j] = *(const short8*)&Bs[cur + (wx * 64 + j * 16 + m16) * 32 + quad * 8];
        #pragma unroll
        for (int i = 0; i < 4; i++)
            #pragma unroll
            for (int j = 0; j < 4; j++)
                acc[i][j] = __builtin_amdgcn_mfma_f32_16x16x32_bf16(af[i], bfv[j], acc[i][j], 0, 0, 0);
        buf = (buf == 2) ? 0 : buf + 1;
    }
}

/* =====================================================================
 * Core B (L2-resident GEMMs: S, PV): BK=64, 2-phase, XOR-swizzled
 * source+read (conflict-free ds_read_b128).  [verified rounds 4/6]
 * ===================================================================== */
__device__ __forceinline__ void mfma_core64(const bf16* __restrict__ Ab, int lda,
                                            const bf16* __restrict__ Bb, int ldb,
                                            int nsteps /* K/64 */, short* As, short* Bs,
                                            f32x4 (&acc)[4][4]) {
    const int tid = threadIdx.x;
    const int lane = tid & 63;
    const int wave = tid >> 6;
    const int wy = wave >> 1, wx = wave & 1;
    const int m16 = lane & 15, quad = lane >> 4;
    const int sr = lane >> 3;
    const int sseg = (lane & 7) ^ sr;
    const bf16* aP = Ab + (size_t)(wave * 8 + sr) * lda + sseg * 8;
    const bf16* bP = Bb + (size_t)(wave * 8 + sr) * ldb + sseg * 8;
    short* aL = As + wave * 512;
    short* bL = Bs + wave * 512;
    #pragma unroll
    for (int r = 0; r < 4; r++) {
        gload_lds16(aP + (size_t)(r * 32) * lda, aL + r * 2048);
        gload_lds16(bP + (size_t)(r * 32) * ldb, bL + r * 2048);
    }
    asm volatile("s_waitcnt vmcnt(0)" ::: "memory");
    __builtin_amdgcn_s_barrier();
    const int swz = m16 & 7;
    for (int ks = 0; ks < nsteps; ks++) {
        const int cur = (ks & 1) * 8192;
        const int nxt = 8192 - cur;
        if (ks + 1 < nsteps) {
            const int ko = (ks + 1) * 64;
            #pragma unroll
            for (int r = 0; r < 4; r++) {
                gload_lds16(aP + (size_t)(r * 32) * lda + ko, aL + nxt + r * 2048);
                gload_lds16(bP + (size_t)(r * 32) * ldb + ko, bL + nxt + r * 2048);
            }
        }
        #pragma unroll
        for (int kk = 0; kk < 2; kk++) {
            short8 af[4], bfv[4];
            #pragma unroll
            for (int i = 0; i < 4; i++)
                af[i] = *(const short8*)&As[cur + (wy * 64 + i * 16 + m16) * 64 +
                                            (((kk * 4 + quad) ^ swz) * 8)];
            #pragma unroll
            for (int j = 0; j < 4; j++)
                bfv[j] = *(const short8*)&Bs[cur + (wx * 64 + j * 16 + m16) * 64 +
                                             (((kk * 4 + quad) ^ swz) * 8)];
            #pragma unroll
            for (int i = 0; i < 4; i++)
                #pragma unroll
                for (int j = 0; j < 4; j++)
                    acc[i][j] = __builtin_amdgcn_mfma_f32_16x16x32_bf16(af[i], bfv[j], acc[i][j], 0, 0, 0);
        }
        asm volatile("s_waitcnt vmcnt(0)" ::: "memory");
        __builtin_amdgcn_s_barrier();
    }
}

/* =====================================================================
 * setup_mega: V^T transpose | K_w,Q_w -> bf16 | u,v,c0 GEMVs | build_g
 * ===================================================================== */
__global__ void setup_mega(const float* __restrict__ V_w,
                           const float* __restrict__ K_w, const float* __restrict__ Q_w,
                           const float* __restrict__ K_b, const float* __restrict__ Q_b,
                           const int* __restrict__ words, const int* __restrict__ pos,
                           const int* __restrict__ ner, const int* __restrict__ chunks,
                           const int* __restrict__ subj_pos, const int* __restrict__ obj_pos,
                           const int* __restrict__ on_path, const float* __restrict__ dep_feat,
                           const float* __restrict__ emb_w, const float* __restrict__ pos_w,
                           const float* __restrict__ ner_w, const float* __restrict__ chunk_w,
                           const float* __restrict__ position_w,
                           bf16* __restrict__ WtV, bf16* __restrict__ Kbf, bf16* __restrict__ Qbf,
                           float* __restrict__ uvbuf, bf16* __restrict__ g) {
    int blk = blockIdx.x, tid = threadIdx.x;
    if (blk < 256) {                          /* V^T: Wt[n][k] = V_w[k][n] */
        __shared__ float t[32][33];
        int n0 = (blk & 15) * 32, k0 = (blk >> 4) * 32;
        int a = tid & 31, bq = tid >> 5;
        #pragma unroll
        for (int it = 0; it < 4; it++) {
            int k = k0 + bq + it * 8, n = n0 + a;
            t[bq + it * 8][a] = (k < ND && n < ND) ? V_w[k * ND + n] : 0.f;
        }
        __syncthreads();
        #pragma unroll
        for (int it = 0; it < 4; it++) {
            int n = n0 + bq + it * 8;
            WtV[(size_t)n * NDP + k0 + a] = __float2bfloat16(t[a][bq + it * 8]);
        }
    } else if (blk < 768) {                   /* cvt K_w -> Kbf (padded) */
        int row = blk - 256;
        bf16* dst = Kbf + (size_t)row * NDP;
        for (int c = tid; c < NDP; c += 256)
            dst[c] = __float2bfloat16((row < ND && c < ND) ? K_w[row * ND + c] : 0.f);
    } else if (blk < 1280) {                  /* cvt Q_w -> Qbf */
        int row = blk - 768;
        bf16* dst = Qbf + (size_t)row * NDP;
        for (int c = tid; c < NDP; c += 256)
            dst[c] = __float2bfloat16((row < ND && c < ND) ? Q_w[row * ND + c] : 0.f);
    } else if (blk < 1288) {                  /* u[k] = K_w[k,:] . Q_b */
        int k = (blk - 1280) * 64 + tid;
        if (tid < 64) {
            float s = 0.f;
            if (k < ND) for (int n = 0; n < ND; n++) s += K_w[(size_t)k * ND + n] * Q_b[n];
            uvbuf[k] = s;
        }
    } else if (blk < 1296) {                  /* v[k] = Q_w[k,:] . K_b */
        int k = (blk - 1288) * 64 + tid;
        if (tid < 64) {
            float s = 0.f;
            if (k < ND) for (int n = 0; n < ND; n++) s += Q_w[(size_t)k * ND + n] * K_b[n];
            uvbuf[512 + k] = s;
        }
    } else if (blk == 1296) {                 /* c0 = K_b . Q_b */
        if (tid == 0) {
            float s = 0.f;
            for (int n = 0; n < ND; n++) s += K_b[n] * Q_b[n];
            uvbuf[1024] = s;
        }
    } else {                                  /* build_g */
        int tok = blk - 1297;
        int w = words[tok], p = pos[tok], n = ner[tok], ck = chunks[tok];
        int sp = subj_pos[tok], op = obj_pos[tok], onp = on_path[tok];
        bf16* gr = g + (size_t)tok * NDP;
        for (int d = tid; d < NDP; d += 256) {
            float v;
            if      (d < 300) v = emb_w[(size_t)w * 300 + d];
            else if (d < 335) v = pos_w[p * 35 + (d - 300)];
            else if (d < 365) v = ner_w[n * 30 + (d - 335)];
            else if (d < 395) v = chunk_w[ck * 30 + (d - 365)];
            else if (d < 425) v = position_w[sp * 30 + (d - 395)];
            else if (d < 455) v = position_w[op * 30 + (d - 425)];
            else if (d == 455) v = (float)onp;
            else if (d < 500) v = dep_feat[(size_t)tok * 44 + (d - 456)];
            else              v = 0.f;
            gr[d] = __float2bfloat16(v);
        }
    }
}

/* ---- M = K_w @ Q_w^T, stored transposed: Mt[k'][k] (B-operand layout) ---- */
__global__ __launch_bounds__(256) void mgemm(const bf16* __restrict__ Kbf, const bf16* __restrict__ Qbf,
                                             bf16* __restrict__ Mt) {
    __shared__ short LB[24576];
    short* As = LB;
    short* Bs = LB + 12288;
    f32x4 acc[4][4] = {};
    int row0 = blockIdx.x * 128, col0 = blockIdx.y * 128;
    mfma_core3(Kbf + (size_t)row0 * NDP, NDP, Qbf + (size_t)col0 * NDP, NDP, NDP / 32, As, Bs, acc);
    const int tid = threadIdx.x, lane = tid & 63, wave = tid >> 6;
    const int wx = wave & 1, wy = wave >> 1, m16 = lane & 15, quad = lane >> 4;
    bf16* Ct = (bf16*)LB;
    __syncthreads();
    #pragma unroll
    for (int h = 0; h < 2; h++) {
        if (wy == h) {
            #pragma unroll
            for (int j = 0; j < 4; j++) {
                int cl = wx * 64 + j * 16 + m16;
                #pragma unroll
                for (int i = 0; i < 4; i++)
                    #pragma unroll
                    for (int reg = 0; reg < 4; reg++)
                        Ct[(i * 16 + quad * 4 + reg) * 128 + cl] = __float2bfloat16(acc[i][j][reg]);
            }
        }
        __syncthreads();
        int cl2 = tid & 127, sh = tid >> 7;
        bf16* dst = Mt + ((size_t)(col0 + cl2)) * NDP + row0 + h * 64 + sh * 32;
        #pragma unroll
        for (int kk = 0; kk < 8; kk++) {
            short4v o;
            #pragma unroll
            for (int e = 0; e < 4; e++)
                ((bf16*)&o)[e] = Ct[(sh * 32 + kk * 4 + e) * 128 + cl2];
            *(short4v*)(dst + kk * 4) = o;
        }
        __syncthreads();
    }
}

/* ---- subj max pool partials: 256 thr (4 t-subslices x 64 dim-lanes) ---- */
__global__ __launch_bounds__(256) void pool_part(const bf16* __restrict__ g,
                                                 const int* __restrict__ subj_pos,
                                                 float* __restrict__ part) {
    int b = blockIdx.x, s = blockIdx.y, tid = threadIdx.x;
    __shared__ float sh[2048];
    int ts = tid >> 6, o = tid & 63;
    const int* sp = subj_pos + b * NT;
    const bf16* gb = g + (size_t)b * NT * NDP + o * 8;
    float mx[8];
    #pragma unroll
    for (int i = 0; i < 8; i++) mx[i] = -INFINITY;
    #pragma unroll
    for (int it = 0; it < 8; it++) {
        int t = s * (NT / TSP) + ts + it * 4;
        int masked = (sp[t] != 0);
        short8 v8 = *(const short8*)(gb + (size_t)t * NDP);
        #pragma unroll
        for (int i = 0; i < 8; i++) {
            float v = masked ? -1e12f : b2f(((bf16*)&v8)[i]);
            mx[i] = fmaxf(mx[i], v);
        }
    }
    #pragma unroll
    for (int i = 0; i < 8; i++) sh[tid * 8 + i] = mx[i];
    __syncthreads();
    if (ts == 0) {
        float r[8];
        #pragma unroll
        for (int i = 0; i < 8; i++) r[i] = sh[o * 8 + i];
        #pragma unroll
        for (int s2 = 1; s2 < 4; s2++)
            #pragma unroll
            for (int i = 0; i < 8; i++) r[i] = fmaxf(r[i], sh[(s2 * 64 + o) * 8 + i]);
        float* pr = part + ((size_t)(b * TSP + s)) * NDP + o * 8;
        #pragma unroll
        for (int i = 0; i < 8; i++) pr[i] = r[i];
    }
}

/* pool-reduce -> subj; q = relu(subj @ (Wq0+Wq1) + bq) */
__global__ __launch_bounds__(512) void gemv_q(const float* __restrict__ part,
                                              const float* __restrict__ Wq_w, const float* __restrict__ Wq_b,
                                              float* __restrict__ subj, float* __restrict__ qb) {
    int b = blockIdx.x, dch = blockIdx.y, tid = threadIdx.x;
    __shared__ float xs[512];
    __shared__ float red[512];
    float mx = -INFINITY;
    #pragma unroll
    for (int s = 0; s < TSP; s++) mx = fmaxf(mx, part[((size_t)(b * TSP + s)) * NDP + tid]);
    xs[tid] = (tid < ND) ? mx : 0.f;
    if (dch == 0 && tid < ND) subj[b * ND + tid] = mx;
    __syncthreads();
    int jg = tid >> 7, dl = tid & 127, d = dch * 128 + dl;
    float acc = 0.f;
    if (d < ND) {
        int j0 = jg * 125;
        const float* w0 = Wq_w + (size_t)j0 * ND + d;
        const float* w1 = w0 + (size_t)ND * ND;
        #pragma unroll 5
        for (int j = 0; j < 125; j++)
            acc += xs[j0 + j] * (w0[(size_t)j * ND] + w1[(size_t)j * ND]);
    }
    red[tid] = acc;
    __syncthreads();
    if (jg == 0 && d < ND) {
        float s = (red[dl] + red[128 + dl]) + (red[256 + dl] + red[384 + dl]);
        qb[b * ND + d] = fmaxf(s + Wq_b[d], 0.f);
    }
}

/* w2 = relu(q @ Wc0 + bc) * Wk */
__global__ __launch_bounds__(512) void gemv_w2(const float* __restrict__ qb,
                                               const float* __restrict__ Wc_w, const float* __restrict__ Wc_b,
                                               const float* __restrict__ Wk_w, float* __restrict__ w2) {
    int b = blockIdx.x, dch = blockIdx.y, tid = threadIdx.x;
    __shared__ float xs[512];
    __shared__ float red[512];
    xs[tid] = (tid < ND) ? qb[b * ND + tid] : 0.f;
    __syncthreads();
    int jg = tid >> 7, dl = tid & 127, d = dch * 128 + dl;
    float acc = 0.f;
    if (d < ND) {
        int j0 = jg * 125;
        const float* w0 = Wc_w + (size_t)j0 * ND + d;
        #pragma unroll 5
        for (int j = 0; j < 125; j++)
            acc += xs[j0 + j] * w0[(size_t)j * ND];
    }
    red[tid] = acc;
    __syncthreads();
    if (jg == 0 && d < ND) {
        float s = (red[dl] + red[128 + dl]) + (red[256 + dl] + red[384 + dl]);
        w2[b * ND + d] = fmaxf(s + Wc_b[d], 0.f) * Wk_w[d];
    }
}

/* c-reduce; m = relu(c @ Wm0 + subj @ (Wm1+Wm2) + bm) */
__global__ __launch_bounds__(512) void gemv_m(const float* __restrict__ part,
                                              const float* __restrict__ subj,
                                              const float* __restrict__ Wm_w, const float* __restrict__ Wm_b,
                                              float* __restrict__ mv) {
    int b = blockIdx.x, dch = blockIdx.y, tid = threadIdx.x;
    __shared__ float cs[512];
    __shared__ float ss[512];
    __shared__ float red[512];
    float a = 0.f;
    #pragma unroll
    for (int s = 0; s < TSP; s++) a += part[((size_t)(b * TSP + s)) * NDP + tid];
    cs[tid] = (tid < ND) ? a : 0.f;
    ss[tid] = (tid < ND) ? subj[b * ND + tid] : 0.f;
    __syncthreads();
    int jg = tid >> 7, dl = tid & 127, d = dch * 128 + dl;
    float acc = 0.f;
    if (d < ND) {
        int j0 = jg * 125;
        const float* w0 = Wm_w + (size_t)j0 * ND + d;
        const float* w1 = w0 + (size_t)ND * ND;
        const float* w2p = w0 + (size_t)2 * ND * ND;
        #pragma unroll 5
        for (int j = 0; j < 125; j++) {
            acc += cs[j0 + j] * w0[(size_t)j * ND];
            acc += ss[j0 + j] * (w1[(size_t)j * ND] + w2p[(size_t)j * ND]);
        }
    }
    red[tid] = acc;
    __syncthreads();
    if (jg == 0 && d < ND) {
        float s = (red[dl] + red[128 + dl]) + (red[256 + dl] + red[384 + dl]);
        mv[b * ND + d] = fmaxf(s + Wm_b[d], 0.f);
    }
}

/* ---- klog + bias-correction vectors a = g.u, b = g.v (one wave/token) ---- */
__global__ void compute_klog3(const bf16* __restrict__ g, const float* __restrict__ w2,
                              const float* __restrict__ Wk_b, const float* __restrict__ uvbuf,
                              float* __restrict__ klog, float* __restrict__ a_vec,
                              float* __restrict__ b_vec) {
    int tok = blockIdx.x * 4 + (threadIdx.x >> 6);
    int lane = threadIdx.x & 63;
    int b = tok >> 10;
    const bf16* gr = g + (size_t)tok * NDP + lane * 8;
    const float* wr = w2 + b * ND + lane * 8;
    const float* ur = uvbuf + lane * 8;
    const float* vr = uvbuf + 512 + lane * 8;
    short8 v8 = *(const short8*)gr;
    float aw = 0.f, au = 0.f, av = 0.f;
    #pragma unroll
    for (int i = 0; i < 8; i++) {
        float gv = b2f(((bf16*)&v8)[i]);
        aw += gv * wr[i]; au += gv * ur[i]; av += gv * vr[i];
    }
    #pragma unroll
    for (int off = 32; off; off >>= 1) {
        aw += __shfl_down(aw, off, 64);
        au += __shfl_down(au, off, 64);
        av += __shfl_down(av, off, 64);
    }
    if (lane == 0) {
        klog[tok] = aw + Wk_b[0];
        a_vec[tok] = au;
        b_vec[tok] = av;
    }
}

/* ---- c = sum_t softmax(klog)*g partials; softmax stats recomputed per block ---- */
__global__ __launch_bounds__(256) void c_part(const bf16* __restrict__ g,
                                              const float* __restrict__ klog,
                                              float* __restrict__ part) {
    int b = blockIdx.x, s = blockIdx.y, tid = threadIdx.x;
    __shared__ float sh[2048];
    const float* kl = klog + b * NT;
    float m = -INFINITY;
    for (int t = tid; t < NT; t += 256) m = fmaxf(m, kl[t]);
    sh[tid] = m; __syncthreads();
    for (int r = 128; r; r >>= 1) { if (tid < r) sh[tid] = fmaxf(sh[tid], sh[tid + r]); __syncthreads(); }
    float mm = sh[0]; __syncthreads();
    float sum = 0.f;
    for (int t = tid; t < NT; t += 256) sum += __expf(kl[t] - mm);
    sh[tid] = sum; __syncthreads();
    for (int r = 128; r; r >>= 1) { if (tid < r) sh[tid] += sh[tid + r]; __syncthreads(); }
    float inv = 1.f / sh[0]; __syncthreads();
    int ts = tid >> 6, o = tid & 63;
    const bf16* gb = g + (size_t)b * NT * NDP + o * 8;
    float acc[8] = {};
    #pragma unroll
    for (int it = 0; it < 8; it++) {
        int t = s * (NT / TSP) + ts + it * 4;
        float kv = __expf(kl[t] - mm) * inv;
        short8 v8 = *(const short8*)(gb + (size_t)t * NDP);
        #pragma unroll
        for (int i = 0; i < 8; i++) acc[i] += kv * b2f(((bf16*)&v8)[i]);
    }
    #pragma unroll
    for (int i = 0; i < 8; i++) sh[tid * 8 + i] = acc[i];
    __syncthreads();
    if (ts == 0) {
        float r[8];
        #pragma unroll
        for (int i = 0; i < 8; i++) r[i] = sh[o * 8 + i];
        #pragma unroll
        for (int s2 = 1; s2 < 4; s2++)
            #pragma unroll
            for (int i = 0; i < 8; i++) r[i] += sh[(s2 * 64 + o) * 8 + i];
        float* pr = part + ((size_t)(b * TSP + s)) * NDP + o * 8;
        #pragma unroll
        for (int i = 0; i < 8; i++) pr[i] = r[i];
    }
}

/* ---- projections: z=0 h=g@M (normal store), z=1 value (transposed Vt store) ---- */
__global__ __launch_bounds__(256) void mfma_proj3(const bf16* __restrict__ g, const bf16* __restrict__ Mt,
                                                  const bf16* __restrict__ WtV, const float* __restrict__ bV,
                                                  bf16* __restrict__ gM, bf16* __restrict__ valT) {
    __shared__ short LB[24576];
    short* As = LB;
    short* Bs = LB + 12288;
    f32x4 acc[4][4] = {};
    const int zz = blockIdx.z;
    const bf16* Wt = (zz == 0) ? Mt : WtV;
    int row0 = blockIdx.x * 128, col0 = blockIdx.y * 128;
    mfma_core3(g + (size_t)row0 * NDP, NDP, Wt + (size_t)col0 * NDP, NDP, NDP / 32, As, Bs, acc);
    const int tid = threadIdx.x, lane = tid & 63, wave = tid >> 6;
    const int wx = wave & 1, wy = wave >> 1, m16 = lane & 15, quad = lane >> 4;
    bf16* Ct = (bf16*)LB;
    int rl = tid >> 4, cs = (tid & 15) * 8;
    int bI = row0 >> 10, sBase = row0 & 1023;
    __syncthreads();
    #pragma unroll
    for (int h = 0; h < 2; h++) {
        if (wy == h) {
            #pragma unroll
            for (int j = 0; j < 4; j++) {
                int cl = wx * 64 + j * 16 + m16;
                int cg = col0 + cl;
                float bv = (zz == 1 && cg < ND) ? bV[cg] : 0.f;
                bool ok = (cg < ND);
                #pragma unroll
                for (int i = 0; i < 4; i++)
                    #pragma unroll
                    for (int reg = 0; reg < 4; reg++)
                        Ct[(i * 16 + quad * 4 + reg) * 128 + cl] =
                            __float2bfloat16(ok ? (acc[i][j][reg] + bv) : 0.f);
            }
        }
        __syncthreads();
        if (zz == 0) {
            #pragma unroll
            for (int p = 0; p < 4; p++) {
                int row_l = p * 16 + rl;
                *(short8*)(gM + (size_t)(row0 + h * 64 + row_l) * NDP + col0 + cs) =
                    *(const short8*)&Ct[row_l * 128 + cs];
            }
        } else {
            int cl2 = tid & 127, sh = tid >> 7;
            bf16* dst = valT + ((size_t)(bI * NDP + col0 + cl2)) * NT + sBase + h * 64 + sh * 32;
            #pragma unroll
            for (int kk = 0; kk < 8; kk++) {
                short4v o;
                #pragma unroll
                for (int e = 0; e < 4; e++)
                    ((bf16*)&o)[e] = Ct[(sh * 32 + kk * 4 + e) * 128 + cl2];
                *(short4v*)(dst + kk * 4) = o;
            }
        }
        __syncthreads();
    }
}

/* ---- MFMA S = (g@M) @ g^T: z-XCD affinity, core64 ---- */
__global__ __launch_bounds__(256) void mfma_S(const bf16* __restrict__ gM, const bf16* __restrict__ g,
                                              bf16* __restrict__ S) {
    __shared__ short LB[32768];
    short* As = LB;
    short* Bs = LB + 16384;
    f32x4 acc[4][4] = {};
    int lin = blockIdx.x;
    int xcd = lin & 7, j = lin >> 3;
    int i = j & 63, z = xcd + 8 * (j >> 6);
    int bx = i & 7, by = i >> 3;
    int row0 = bx * 128, col0 = by * 128;
    const bf16* kb = gM + (size_t)z * NT * NDP;
    const bf16* qb = g + (size_t)z * NT * NDP;
    mfma_core64(kb + (size_t)row0 * NDP, NDP, qb + (size_t)col0 * NDP, NDP, NDP / 64, As, Bs, acc);
    bf16* Sb = S + ((size_t)z << 20);
    const int tid = threadIdx.x, lane = tid & 63, wave = tid >> 6;
    const int wx = wave & 1, wy = wave >> 1, m16 = lane & 15, quad = lane >> 4;
    bf16* Ct = (bf16*)LB;
    int rl = tid >> 4, cs = (tid & 15) * 8;
    __syncthreads();
    #pragma unroll
    for (int h = 0; h < 2; h++) {
        if (wy == h) {
            #pragma unroll
            for (int j2 = 0; j2 < 4; j2++) {
                int cl = wx * 64 + j2 * 16 + m16;
                #pragma unroll
                for (int i2 = 0; i2 < 4; i2++)
                    #pragma unroll
                    for (int reg = 0; reg < 4; reg++)
                        Ct[(i2 * 16 + quad * 4 + reg) * 128 + cl] = __float2bfloat16(acc[i2][j2][reg]);
            }
        }
        __syncthreads();
        #pragma unroll
        for (int p = 0; p < 4; p++) {
            int row_l = p * 16 + rl;
            *(short8*)(Sb + (((size_t)(row0 + h * 64 + row_l)) << 10) + col0 + cs) =
                *(const short8*)&Ct[row_l * 128 + cs];
        }
        __syncthreads();
    }
}

/* ---- double softmax with bias terms a[t]+b[s]+c0; in-place P2 ---- */
__global__ __launch_bounds__(256) void attn_rows(bf16* __restrict__ S,
                                                 const float* __restrict__ a_vec,
                                                 const float* __restrict__ b_vec,
                                                 const float* __restrict__ uvbuf,
                                                 float* __restrict__ att_out) {
    int lin = blockIdx.x;
    int xcd = lin & 7, t2 = lin >> 3;
    int i2 = t2 & 255, zh = t2 >> 8;
    int z = xcd + 8 * zh;
    int gr = z * 1024 + i2 * 4 + (threadIdx.x >> 6);
    int t = gr & 1023;
    int lane = threadIdx.x & 63;
    bf16* row = S + ((size_t)gr << 10) + lane * 16;
    short8 r0 = *(const short8*)row;
    short8 r1 = *(const short8*)(row + 8);
    float add = a_vec[gr] + uvbuf[1024];
    const float* bvp = b_vec + ((size_t)z << 10) + lane * 16;
    f32x4 bv0 = *(const f32x4*)(bvp);
    f32x4 bv1 = *(const f32x4*)(bvp + 4);
    f32x4 bv2 = *(const f32x4*)(bvp + 8);
    f32x4 bv3 = *(const f32x4*)(bvp + 12);
    float v[16];
    #pragma unroll
    for (int i = 0; i < 8; i++) { v[i] = b2f(((bf16*)&r0)[i]); v[8 + i] = b2f(((bf16*)&r1)[i]); }
    #pragma unroll
    for (int i = 0; i < 4; i++) {
        v[i]      += add + bv0[i];
        v[4 + i]  += add + bv1[i];
        v[8 + i]  += add + bv2[i];
        v[12 + i] += add + bv3[i];
    }
    float m = -INFINITY;
    #pragma unroll
    for (int i = 0; i < 16; i++) m = fmaxf(m, v[i]);
    #pragma unroll
    for (int off = 32; off; off >>= 1) m = fmaxf(m, __shfl_xor(m, off, 64));
    float s1 = 0.f, s2 = 0.f, dg = 0.f;
    int tloc = t - lane * 16;
    #pragma unroll
    for (int i = 0; i < 16; i++) {
        float e1 = __expf(v[i] - m);
        float e2 = __expf((v[i] - m) * INV_SCALE);
        s1 += e1; s2 += e2;
        if (i == tloc) dg = e1;
        v[i] = e2;
    }
    #pragma unroll
    for (int off = 32; off; off >>= 1) {
        s1 += __shfl_xor(s1, off, 64);
        s2 += __shfl_xor(s2, off, 64);
        dg += __shfl_xor(dg, off, 64);
    }
    if (lane == 0) att_out[gr] = (1.f - dg / s1) * INV_SCALE;
    float inv2 = 1.f / s2;
    #pragma unroll
    for (int i = 0; i < 8; i++) {
        ((bf16*)&r0)[i] = __float2bfloat16(v[i] * inv2);
        ((bf16*)&r1)[i] = __float2bfloat16(v[8 + i] * inv2);
    }
    *(short8*)row = r0;
    *(short8*)(row + 8) = r1;
}

/* ---- MFMA PV: z-XCD affinity, core64 ---- */
__global__ __launch_bounds__(256) void mfma_PV(const bf16* __restrict__ S, const bf16* __restrict__ valueT,
                                               const float* __restrict__ mvec, float* __restrict__ outp) {
    __shared__ short LB[32768];
    short* As = LB;
    short* Bs = LB + 16384;
    f32x4 acc[4][4] = {};
    int lin = blockIdx.x;
    int xcd = lin & 7, j = lin >> 3;
    int i = j & 31, z = xcd + 8 * (j >> 5);
    int bx = i & 7, by = i >> 3;
    int row0 = bx * 128, col0 = by * 128;
    const bf16* P2 = S + ((size_t)z << 20);
    const bf16* Vt = valueT + (size_t)z * NDP * NT;
    mfma_core64(P2 + (size_t)row0 * NT, NT, Vt + (size_t)col0 * NT, NT, NT / 64, As, Bs, acc);
    const int tid = threadIdx.x, lane = tid & 63, wave = tid >> 6;
    const int wx = wave & 1, wy = wave >> 1, m16 = lane & 15, quad = lane >> 4;
    float* Ct = (float*)LB;
    int rl = tid >> 4, cs = (tid & 15) * 8;
    __syncthreads();
    #pragma unroll
    for (int h = 0; h < 2; h++) {
        if (wy == h) {
            #pragma unroll
            for (int j2 = 0; j2 < 4; j2++) {
                int cl = wx * 64 + j2 * 16 + m16;
                int cg = col0 + cl;
                float mm = (cg < ND) ? mvec[z * ND + cg] : 0.f;
                #pragma unroll
                for (int i2 = 0; i2 < 4; i2++)
                    #pragma unroll
                    for (int reg = 0; reg < 4; reg++)
                        Ct[(i2 * 16 + quad * 4 + reg) * 128 + cl] = acc[i2][j2][reg] * mm;
            }
        }
        __syncthreads();
        #pragma unroll
        for (int p = 0; p < 4; p++) {
            int row_l = p * 16 + rl;
            int r = row0 + h * 64 + row_l;
            float* orow = outp + (size_t)(z * NT + r) * ND + col0 + cs;
            const float* src = &Ct[row_l * 128 + cs];
            if (col0 + cs + 8 <= ND) {
                *(f32x4*)orow = *(const f32x4*)src;
                *(f32x4*)(orow + 4) = *(const f32x4*)(src + 4);
            } else {
                #pragma unroll
                for (int e = 0; e < 8; e++)
                    if (col0 + cs + e < ND) orow[e] = src[e];
            }
        }
        __syncthreads();
    }
}

extern "C" void kernel_launch(void* const* d_in, const int* in_sizes, int n_in,
                              void* d_out, int out_size, void* d_ws, size_t ws_size,
                              hipStream_t stream) {
    const int*   words     = (const int*)d_in[0];
    const int*   pos       = (const int*)d_in[2];
    const int*   ner       = (const int*)d_in[3];
    const int*   subj_pos  = (const int*)d_in[4];
    const int*   obj_pos   = (const int*)d_in[5];
    const int*   chunks    = (const int*)d_in[6];
    const int*   on_path   = (const int*)d_in[7];
    const float* dep_feat  = (const float*)d_in[8];
    const float* emb_w     = (const float*)d_in[9];
    const float* pos_w     = (const float*)d_in[10];
    const float* ner_w     = (const float*)d_in[11];
    const float* chunk_w   = (const float*)d_in[12];
    const float* position_w= (const float*)d_in[13];
    const float* Wq_w      = (const float*)d_in[14];
    const float* Wq_b      = (const float*)d_in[15];
    const float* Wc_w      = (const float*)d_in[16];
    const float* Wc_b      = (const float*)d_in[17];
    const float* Wk_w      = (const float*)d_in[18];
    const float* Wk_b      = (const float*)d_in[19];
    const float* Wm_w      = (const float*)d_in[20];
    const float* Wm_b      = (const float*)d_in[21];
    const float* K_w       = (const float*)d_in[22];
    const float* K_b       = (const float*)d_in[23];
    const float* Q_w       = (const float*)d_in[24];
    const float* Q_b       = (const float*)d_in[25];
    const float* V_w       = (const float*)d_in[26];
    const float* V_b       = (const float*)d_in[27];

    float* out_main = (float*)d_out;
    float* out_att  = out_main + (size_t)NTOK * ND;

    /* ---- ws layout ---- */
    char* wp = (char*)d_ws;
    float* subj = (float*)wp; wp += (size_t)NB * ND * 4;
    float* qb   = (float*)wp; wp += (size_t)NB * ND * 4;
    float* w2   = (float*)wp; wp += (size_t)NB * ND * 4;
    float* cb   = (float*)wp; wp += (size_t)NB * ND * 4;   /* unused */
    float* mv   = (float*)wp; wp += (size_t)NB * ND * 4;
    float* klog = (float*)wp; wp += (size_t)NB * NT * 4;
    float* kbuf = (float*)wp; wp += (size_t)NB * NT * 4;   /* unused (kept for layout) */
    float* part = (float*)wp; wp += (size_t)NB * TSP * NDP * 4;
    bf16* g     = (bf16*)wp;  wp += (size_t)NTOK * NDP * 2;
    bf16* Wt    = (bf16*)wp;  wp += (size_t)3 * NDP * NDP * 2;   /* slot0=V^T, slot1=Mt */
    bf16* kqv   = (bf16*)wp;  wp += (size_t)3 * NTOK * NDP * 2;  /* slot0=gM; slot1 carved below */
    bf16* valT  = (bf16*)wp;  wp += (size_t)NTOK * NDP * 2;
    bf16* S     = (bf16*)wp;                                     /* 32 MB */

    bf16* WtV = Wt;
    bf16* Mt  = Wt + (size_t)NDP * NDP;
    bf16* gM  = kqv;
    bf16* Kbf = kqv + (size_t)NTOK * NDP;
    bf16* Qbf = Kbf + (size_t)NDP * NDP;
    float* uvbuf = (float*)(Qbf + (size_t)NDP * NDP);   /* u[512] v[512] c0 */
    float* a_vec = uvbuf + 2048;
    float* b_vec = a_vec + NTOK;
    (void)cb; (void)kbuf;

    /* setup: V^T | K/Q->bf16 | u,v,c0 | build_g */
    setup_mega<<<1297 + NTOK, 256, 0, stream>>>(V_w, K_w, Q_w, K_b, Q_b,
                                                words, pos, ner, chunks, subj_pos, obj_pos,
                                                on_path, dep_feat, emb_w, pos_w, ner_w,
                                                chunk_w, position_w, WtV, Kbf, Qbf, uvbuf, g);
    mgemm<<<dim3(4, 4), 256, 0, stream>>>(Kbf, Qbf, Mt);

    /* phase A (separate launches; cooperative fusion regressed in round 7) */
    pool_part<<<dim3(NB, TSP), 256, 0, stream>>>(g, subj_pos, part);
    gemv_q<<<dim3(NB, 4), 512, 0, stream>>>(part, Wq_w, Wq_b, subj, qb);
    gemv_w2<<<dim3(NB, 4), 512, 0, stream>>>(qb, Wc_w, Wc_b, Wk_w, w2);
    compute_klog3<<<NTOK / 4, 256, 0, stream>>>(g, w2, Wk_b, uvbuf, klog, a_vec, b_vec);
    c_part<<<dim3(NB, TSP), 256, 0, stream>>>(g, klog, part);
    gemv_m<<<dim3(NB, 4), 512, 0, stream>>>(part, subj, Wm_w, Wm_b, mv);

    /* phase B */
    mfma_proj3<<<dim3(NTOK / 128, NDP / 128, 2), 256, 0, stream>>>(g, Mt, WtV, V_b, gM, valT);
    mfma_S<<<1024, 256, 0, stream>>>(gM, g, S);
    attn_rows<<<NTOK / 4, 256, 0, stream>>>(S, a_vec, b_vec, uvbuf, out_att);
    mfma_PV<<<512, 256, 0, stream>>>(S, valT, mv, out_main);

    (void)in_sizes; (void)n_in; (void)out_size; (void)ws_size;
}